// Round 2
// baseline (407.990 us; speedup 1.0000x reference)
//
#include <hip/hip_runtime.h>

// HistogramOfFeaturesModel: B=4096 rows, F=16384, BINS=128, OUT=64.
// One 256-thread block per row, 8 blocks/CU. Two passes over the row
// (pass 2 hits L2/L3). Histogram copies indexed by tid&15 with stride-129
// padding: kills same-address atomic serialization AND bank clustering.

#define BINS    128
#define FEAT    16384
#define NOUT    64
#define TPB     256
#define NWAVE   (TPB / 64)        // 4
#define NCPY    16                // histogram copies, selected by tid&15
#define HSTRIDE 129               // +1 pad word -> banks spread across copies
#define NFEATS  (2 * BINS + 1)    // 257
#define PER_T4  (FEAT / 4 / TPB)  // 16 float4 per thread per pass

__global__ __launch_bounds__(TPB, 8) void hist_row_kernel(
    const float* __restrict__ x,
    const float* __restrict__ W,
    const float* __restrict__ b,
    float* __restrict__ out)
{
    __shared__ unsigned int s_hist[NCPY * HSTRIDE];   // 8.25 KB
    __shared__ float s_red[2 * NWAVE];
    __shared__ float s_counts[BINS];
    __shared__ float s_mm[2];

    const int row  = blockIdx.x;
    const int tid  = threadIdx.x;
    const int lane = tid & 63;
    const int wave = tid >> 6;

    // zero histogram copies (2064 words, ~8 per thread)
    for (int i = tid; i < NCPY * HSTRIDE; i += TPB) s_hist[i] = 0u;

    // ---- pass 1: streaming min/max (no register cache) ----
    const float4* xr = (const float4*)(x + (size_t)row * FEAT);
    float mn = INFINITY, mx = -INFINITY;
    #pragma unroll 4
    for (int i = 0; i < PER_T4; ++i) {
        float4 t = xr[i * TPB + tid];
        mn = fminf(mn, fminf(fminf(t.x, t.y), fminf(t.z, t.w)));
        mx = fmaxf(mx, fmaxf(fmaxf(t.x, t.y), fmaxf(t.z, t.w)));
    }
    #pragma unroll
    for (int off = 32; off; off >>= 1) {
        mn = fminf(mn, __shfl_down(mn, off));
        mx = fmaxf(mx, __shfl_down(mx, off));
    }
    if (lane == 0) { s_red[wave] = mn; s_red[NWAVE + wave] = mx; }
    __syncthreads();
    if (tid == 0) {
        float a = s_red[0], c = s_red[NWAVE];
        #pragma unroll
        for (int i = 1; i < NWAVE; ++i) {
            a = fminf(a, s_red[i]);
            c = fmaxf(c, s_red[NWAVE + i]);
        }
        s_mm[0] = a; s_mm[1] = c;
    }
    __syncthreads();
    const float rmn   = s_mm[0];
    const float width = s_mm[1] - rmn;
    const float scale = (float)BINS / (width == 0.0f ? 1.0f : width);

    // ---- pass 2: histogram; copy chosen by lane group (tid&15) so
    // same-bin lanes in one instruction hit different addresses ----
    unsigned int* hc = s_hist + (tid & (NCPY - 1)) * HSTRIDE;
    #pragma unroll 2
    for (int i = 0; i < PER_T4; ++i) {
        float4 t = xr[i * TPB + tid];   // L2/L3 hit: row streamed moments ago
        const float vv[4] = {t.x, t.y, t.z, t.w};
        #pragma unroll
        for (int k = 0; k < 4; ++k) {
            int idx = (int)floorf((vv[k] - rmn) * scale);
            idx = idx < 0 ? 0 : (idx > BINS - 1 ? BINS - 1 : idx);
            atomicAdd(&hc[idx], 1u);
        }
    }
    __syncthreads();

    // ---- reduce 16 copies; density normalize (sum is exactly FEAT) ----
    if (tid < BINS) {
        unsigned int s = 0;
        #pragma unroll
        for (int c = 0; c < NCPY; ++c) s += s_hist[c * HSTRIDE + tid];
        s_counts[tid] = (float)s * (1.0f / (float)FEAT);
    }
    __syncthreads();

    // ---- fused epilogue: 4 threads per output column ----
    const int o   = tid >> 2;   // 0..63
    const int sub = tid & 3;
    float acc = 0.0f;
    const float* Wo = W + o * NFEATS;
    for (int j = sub; j < NFEATS; j += 4) {
        const float f = (j < BINS)
            ? s_counts[j]
            : rmn + (float)(j - BINS) * (1.0f / (float)BINS) * width;
        acc += f * Wo[j];
    }
    acc += __shfl_down(acc, 2, 4);
    acc += __shfl_down(acc, 1, 4);
    if (sub == 0) out[(size_t)row * NOUT + o] = acc + b[o];
}

extern "C" void kernel_launch(void* const* d_in, const int* in_sizes, int n_in,
                              void* d_out, int out_size, void* d_ws, size_t ws_size,
                              hipStream_t stream) {
    const float* x = (const float*)d_in[0];   // [4096, 16384]
    const float* W = (const float*)d_in[1];   // [64, 257]
    const float* b = (const float*)d_in[2];   // [64]
    float* out = (float*)d_out;               // [4096, 64]

    hist_row_kernel<<<4096, TPB, 0, stream>>>(x, W, b, out);
}

// Round 3
// 367.522 us; speedup vs baseline: 1.1101x; 1.1101x over previous
//
#include <hip/hip_runtime.h>

// HistogramOfFeaturesModel: B=4096 rows, F=16384, BINS=128, OUT=64.
// Purely HBM-read-bound: x = 256 MiB, floor ~43 us at achievable BW.
// One 1024-thread block per row; each thread caches its 16 floats in
// registers so x is read from HBM exactly ONCE (R2 showed a second pass
// costs +40 us — L2/L3 does not absorb it). Histogram: 16 LDS copies
// selected by tid&15 with stride-129 padding -> same-address atomic
// multiplicity <=4 and conflict-free banks across copies.

#define BINS    128
#define FEAT    16384
#define NOUT    64
#define TPB     1024
#define NWAVE   (TPB / 64)        // 16 waves
#define NCPY    16                // histogram copies, selected by tid&15
#define HSTRIDE 129               // pad word: bank = (copy + bin) % 32
#define PER_T   (FEAT / TPB)      // 16 floats per thread
#define NFEATS  (2 * BINS + 1)    // 257

__global__ __launch_bounds__(TPB) void hist_row_kernel(
    const float* __restrict__ x,
    const float* __restrict__ W,
    const float* __restrict__ b,
    float* __restrict__ out)
{
    __shared__ unsigned int s_hist[NCPY * HSTRIDE];   // 8.25 KB
    __shared__ float s_red[2 * NWAVE];
    __shared__ float s_counts[BINS];
    __shared__ float s_mm[2];

    const int row  = blockIdx.x;
    const int tid  = threadIdx.x;
    const int lane = tid & 63;
    const int wave = tid >> 6;

    // zero histogram copies (2064 words, ~2 per thread)
    for (int i = tid; i < NCPY * HSTRIDE; i += TPB) s_hist[i] = 0u;

    // ---- single pass: row -> registers (coalesced float4), min/max ----
    const float4* xr = (const float4*)(x + (size_t)row * FEAT);
    float4 v[PER_T / 4];
    float mn = INFINITY, mx = -INFINITY;
    #pragma unroll
    for (int c = 0; c < PER_T / 4; ++c) {
        v[c] = xr[c * TPB + tid];
        mn = fminf(mn, fminf(fminf(v[c].x, v[c].y), fminf(v[c].z, v[c].w)));
        mx = fmaxf(mx, fmaxf(fmaxf(v[c].x, v[c].y), fmaxf(v[c].z, v[c].w)));
    }

    // ---- block min/max reduction ----
    #pragma unroll
    for (int off = 32; off; off >>= 1) {
        mn = fminf(mn, __shfl_down(mn, off));
        mx = fmaxf(mx, __shfl_down(mx, off));
    }
    if (lane == 0) { s_red[wave] = mn; s_red[NWAVE + wave] = mx; }
    __syncthreads();
    if (tid == 0) {
        float a = s_red[0], c = s_red[NWAVE];
        #pragma unroll
        for (int i = 1; i < NWAVE; ++i) {
            a = fminf(a, s_red[i]);
            c = fmaxf(c, s_red[NWAVE + i]);
        }
        s_mm[0] = a; s_mm[1] = c;
    }
    __syncthreads();
    const float rmn   = s_mm[0];
    const float width = s_mm[1] - rmn;
    // exact reference arithmetic: BINS / where(width==0, 1, width)
    const float scale = (float)BINS / (width == 0.0f ? 1.0f : width);

    // ---- histogram from registers; copy chosen by tid&15 so same-bin
    // lanes within one ds_add spread across 16 copies (mult <= 4) ----
    unsigned int* hc = s_hist + (tid & (NCPY - 1)) * HSTRIDE;
    #pragma unroll
    for (int c = 0; c < PER_T / 4; ++c) {
        const float vv[4] = {v[c].x, v[c].y, v[c].z, v[c].w};
        #pragma unroll
        for (int k = 0; k < 4; ++k) {
            int idx = (int)floorf((vv[k] - rmn) * scale);
            idx = idx < 0 ? 0 : (idx > BINS - 1 ? BINS - 1 : idx);
            atomicAdd(&hc[idx], 1u);
        }
    }
    __syncthreads();

    // ---- reduce 16 copies; density normalize (sum is exactly FEAT) ----
    if (tid < BINS) {
        unsigned int s = 0;
        #pragma unroll
        for (int c = 0; c < NCPY; ++c) s += s_hist[c * HSTRIDE + tid];
        s_counts[tid] = (float)s * (1.0f / (float)FEAT);
    }
    __syncthreads();

    // ---- fused epilogue: 16 threads per output column ----
    // feats[j] = counts[j] (j<128); feats[128+k] = rmn + (k/128)*width
    const int o   = tid >> 4;   // 0..63
    const int sub = tid & 15;
    float acc = 0.0f;
    const float* Wo = W + o * NFEATS;
    for (int j = sub; j < NFEATS; j += 16) {
        const float f = (j < BINS)
            ? s_counts[j]
            : rmn + (float)(j - BINS) * (1.0f / (float)BINS) * width;
        acc += f * Wo[j];
    }
    #pragma unroll
    for (int off = 8; off; off >>= 1)
        acc += __shfl_down(acc, off, 16);
    if (sub == 0) out[(size_t)row * NOUT + o] = acc + b[o];
}

extern "C" void kernel_launch(void* const* d_in, const int* in_sizes, int n_in,
                              void* d_out, int out_size, void* d_ws, size_t ws_size,
                              hipStream_t stream) {
    const float* x = (const float*)d_in[0];   // [4096, 16384]
    const float* W = (const float*)d_in[1];   // [64, 257]
    const float* b = (const float*)d_in[2];   // [64]
    float* out = (float*)d_out;               // [4096, 64]

    hist_row_kernel<<<4096, TPB, 0, stream>>>(x, W, b, out);
}